// Round 2
// baseline (511.896 us; speedup 1.0000x reference)
//
#include <hip/hip_runtime.h>
#include <stdint.h>
#include <stddef.h>

// BitLinear on MI355X: out[m,o] = sx[m] * sw * sum_i qx[m,i]*qw[o,i]
//   qx: per-row int8 absmax fake-quant of x, qw: ternary {-1,0,1} from absmean.
// Integer inner product exact; only scales carry float rounding.
// R2: fragment-order LDS layout in GEMM (conflict-free ds_read_b128),
//     k_wscale fused into k_wq, k_xq uses reciprocal-mul (flip cost ~2.5e-4).

#define K_DIM 4096
#define M_DIM 8192
#define N_DIM 4096

typedef int v4i __attribute__((ext_vector_type(4)));

__device__ __forceinline__ void async_copy16(void* lds, const void* g) {
  __builtin_amdgcn_global_load_lds(
      (const __attribute__((address_space(1))) unsigned int*)g,
      (__attribute__((address_space(3))) unsigned int*)lds,
      16, 0, 0);
}

// ---------------- kernel 1: per-block partial sums of |w| (double) ----------
__global__ void k_wsum(const float* __restrict__ w, double* __restrict__ partials) {
  const float4* w4 = (const float4*)w;
  int tid = blockIdx.x * 256 + threadIdx.x;          // 262144 threads
  double s = 0.0;
  for (int i = tid; i < 4194304; i += 262144) {      // 16 iters
    float4 v = w4[i];
    s += (double)fabsf(v.x) + (double)fabsf(v.y) +
         (double)fabsf(v.z) + (double)fabsf(v.w);
  }
  for (int off = 32; off > 0; off >>= 1) s += __shfl_down(s, off);
  __shared__ double lsum[4];
  int lane = threadIdx.x & 63, wid = threadIdx.x >> 6;
  if (lane == 0) lsum[wid] = s;
  __syncthreads();
  if (threadIdx.x == 0)
    partials[blockIdx.x] = lsum[0] + lsum[1] + lsum[2] + lsum[3];
}

// ---------------- kernel 2: reduce partials -> scale; ternary-quantize w ----
__global__ void k_wq(const float* __restrict__ w, const double* __restrict__ partials,
                     float* __restrict__ wscale, char* __restrict__ qw) {
  // every block reduces the 1024 partials itself (8KB; removes a launch)
  double s = 0.0;
  for (int i = threadIdx.x; i < 1024; i += 256) s += partials[i];
  for (int off = 32; off > 0; off >>= 1) s += __shfl_down(s, off);
  __shared__ double lsum[4];
  __shared__ float bsc;
  int lane = threadIdx.x & 63, wid = threadIdx.x >> 6;
  if (lane == 0) lsum[wid] = s;
  __syncthreads();
  if (threadIdx.x == 0) {
    double tot = lsum[0] + lsum[1] + lsum[2] + lsum[3];
    float sc = (float)(tot / 16777216.0);            // mean(|w|)
    bsc = sc;
    if (blockIdx.x == 0) *wscale = sc;               // raw scale for epilogue
  }
  __syncthreads();
  float d = bsc + 1e-8f;                             // ref divisor
  const float4* w4 = (const float4*)w;
  int* q4 = (int*)qw;
  int tid = blockIdx.x * 256 + threadIdx.x;          // 2048*256 = 524288 threads
  for (int i = tid; i < 4194304; i += 524288) {      // 8 iters
    float4 v = w4[i];
    // true fp32 division + rint (half-even): a ternary flip costs 0.032 in out
    int a = (int)fmaxf(fminf(rintf(v.x / d), 1.f), -1.f);
    int b = (int)fmaxf(fminf(rintf(v.y / d), 1.f), -1.f);
    int c = (int)fmaxf(fminf(rintf(v.z / d), 1.f), -1.f);
    int e = (int)fmaxf(fminf(rintf(v.w / d), 1.f), -1.f);
    q4[i] = (a & 255) | ((b & 255) << 8) | ((c & 255) << 16) | ((e & 255) << 24);
  }
}

// ---------------- kernel 3: per-row activation quantize -> int8 + scale -----
__global__ void k_xq(const float* __restrict__ x, char* __restrict__ qx,
                     float* __restrict__ sx) {
  int row = blockIdx.x;                               // 8192 rows
  const float4* xr = (const float4*)(x + (size_t)row * K_DIM);
  float4 v[4];
  float m = 0.f;
#pragma unroll
  for (int c = 0; c < 4; c++) {
    v[c] = xr[threadIdx.x + c * 256];
    m = fmaxf(m, fmaxf(fmaxf(fabsf(v[c].x), fabsf(v[c].y)),
                       fmaxf(fabsf(v[c].z), fabsf(v[c].w))));
  }
  for (int off = 32; off > 0; off >>= 1) m = fmaxf(m, __shfl_down(m, off));
  __shared__ float lm[4];
  __shared__ float bscale;
  int lane = threadIdx.x & 63, wid = threadIdx.x >> 6;
  if (lane == 0) lm[wid] = m;
  __syncthreads();
  if (threadIdx.x == 0) {
    float mm = fmaxf(fmaxf(lm[0], lm[1]), fmaxf(lm[2], lm[3]));
    float sc = fmaxf(mm / 127.0f, 1e-8f);            // exact scale (matches ref)
    bscale = sc;
    sx[row] = sc;
  }
  __syncthreads();
  // reciprocal multiply: a +-1 flip in qx costs only sx*sw ~ 2.5e-4 in out
  float inv = 1.0f / bscale;
  int* q4 = (int*)(qx + (size_t)row * K_DIM);
#pragma unroll
  for (int c = 0; c < 4; c++) {
    int a = (int)fmaxf(fminf(rintf(v[c].x * inv), 127.f), -127.f);
    int b = (int)fmaxf(fminf(rintf(v[c].y * inv), 127.f), -127.f);
    int cc = (int)fmaxf(fminf(rintf(v[c].z * inv), 127.f), -127.f);
    int e = (int)fmaxf(fminf(rintf(v[c].w * inv), 127.f), -127.f);
    q4[threadIdx.x + c * 256] = (a & 255) | ((b & 255) << 8) | ((cc & 255) << 16) | ((e & 255) << 24);
  }
}

// ---------------- kernel 4: int8 MFMA GEMM, fragment-order LDS --------------
// 128x128 C-tile per block, 4 waves (2x2 of 64x64), BK=64 int8.
// LDS = 8 chunks of 1024B per operand; chunk c holds rows [c*16, c*16+16) with
// offset l*16 <-> (row c*16+(l&15), kbytes (l>>4)*16) == lane l's MFMA fragment.
// Compute-phase ds_read_b128 is then 64 lanes x 16B contiguous: conflict-free.
__global__ void k_gemm(const char* __restrict__ qx, const char* __restrict__ qw,
                       const float* __restrict__ sx, const float* __restrict__ wscale,
                       float* __restrict__ out) {
  __shared__ char ldsA[8192];
  __shared__ char ldsB[8192];

  const int bn = blockIdx.x & 31;          // 32 tiles along N
  const int bm = blockIdx.x >> 5;          // 64 tiles along M
  const int rowBase = bm * 128;
  const int colBase = bn * 128;
  const int tid = threadIdx.x;
  const int lane = tid & 63;
  const int wave = tid >> 6;
  const int wr = wave >> 1, wc = wave & 1;

  v4i acc[4][4] = {};

  // staging: wave w stages chunks 2w and 2w+1 of each operand.
  // lane l fetches global (row chunk*16 + (l&15), kseg (l>>4)*16) -> lds l*16.
  const int fr = lane & 15;
  const int fk = (lane >> 4) * 16;
  const char* gA0 = qx + (size_t)(rowBase + wave * 32 + fr) * K_DIM + fk;
  const char* gA1 = gA0 + 16 * K_DIM;
  const char* gB0 = qw + (size_t)(colBase + wave * 32 + fr) * K_DIM + fk;
  const char* gB1 = gB0 + 16 * K_DIM;
  char* lA0 = ldsA + wave * 2048;          // wave-uniform LDS bases
  char* lA1 = lA0 + 1024;
  char* lB0 = ldsB + wave * 2048;
  char* lB1 = lB0 + 1024;

  // compute-phase: fragment t lives at chunk (wq*4+t)*1024 + lane*16
  const char* aBase = ldsA + wr * 4096 + lane * 16;
  const char* bBase = ldsB + wc * 4096 + lane * 16;

  for (int kb = 0; kb < K_DIM / 64; kb++) {
    if (kb) __syncthreads();
    const int goff = kb * 64;
    async_copy16(lA0, gA0 + goff);
    async_copy16(lA1, gA1 + goff);
    async_copy16(lB0, gB0 + goff);
    async_copy16(lB1, gB1 + goff);
    __syncthreads();                       // drains vmcnt for the DMA

    v4i a[4], b[4];
#pragma unroll
    for (int t = 0; t < 4; t++) {
      a[t] = *(const v4i*)(aBase + t * 1024);
      b[t] = *(const v4i*)(bBase + t * 1024);
    }
#pragma unroll
    for (int mt = 0; mt < 4; mt++)
#pragma unroll
      for (int nt = 0; nt < 4; nt++)
        acc[mt][nt] = __builtin_amdgcn_mfma_i32_16x16x64_i8(a[mt], b[nt], acc[mt][nt], 0, 0, 0);
  }

  // epilogue: C/D 16x16 layout col=lane&15, row=(lane>>4)*4+reg
  const float sw = *wscale;
  const int col0 = colBase + wc * 64 + (lane & 15);
  const int row0 = rowBase + wr * 64 + (lane >> 4) * 4;
#pragma unroll
  for (int mt = 0; mt < 4; mt++) {
#pragma unroll
    for (int r = 0; r < 4; r++) {
      const int row = row0 + mt * 16 + r;
      const float s = sx[row] * sw;
#pragma unroll
      for (int nt = 0; nt < 4; nt++)
        out[(size_t)row * N_DIM + col0 + nt * 16] = (float)acc[mt][nt][r] * s;
    }
  }
}

// ---------------- launcher ---------------------------------------------------
extern "C" void kernel_launch(void* const* d_in, const int* in_sizes, int n_in,
                              void* d_out, int out_size, void* d_ws, size_t ws_size,
                              hipStream_t stream) {
  const float* x = (const float*)d_in[0];   // [2,4096,4096]
  const float* w = (const float*)d_in[1];   // [4096,4096]
  float* out = (float*)d_out;               // [2,4096,4096]
  char* ws = (char*)d_ws;

  double* partials = (double*)ws;                  // 1024 doubles  @ 0
  float* wscale    = (float*)(ws + 8192);          // 1 float
  float* sx        = (float*)(ws + 8448);          // 8192 floats
  char*  qw        = ws + 41472;                   // 16 MiB
  char*  qx        = ws + 41472 + 16777216;        // 32 MiB

  k_wsum <<<1024, 256, 0, stream>>>(w, partials);
  k_wq   <<<2048, 256, 0, stream>>>(w, partials, wscale, qw);
  k_xq   <<<8192, 256, 0, stream>>>(x, qx, sx);
  k_gemm <<<64 * 32, 256, 0, stream>>>(qx, qw, sx, wscale, out);
}

// Round 3
// 422.978 us; speedup vs baseline: 1.2102x; 1.2102x over previous
//
#include <hip/hip_runtime.h>
#include <stdint.h>
#include <stddef.h>

// BitLinear on MI355X: out[m,o] = sx[m] * sw * sum_i qx[m,i]*qw[o,i]
// R3: swizzled LDS staging layout pos(r,q) = 4r + ((q + (r>>1)) & 3):
//     - staging lane-quads read one 64B row segment (R1's global coalescing)
//     - compute octets hit 8 distinct bank quads (R2's zero conflicts)
//     Also fuses k_wsum into k_xq's dispatch (one fewer serialized launch).

#define K_DIM 4096
#define M_DIM 8192
#define N_DIM 4096

typedef int v4i __attribute__((ext_vector_type(4)));

__device__ __forceinline__ void async_copy16(void* lds, const void* g) {
  __builtin_amdgcn_global_load_lds(
      (const __attribute__((address_space(1))) unsigned int*)g,
      (__attribute__((address_space(3))) unsigned int*)lds,
      16, 0, 0);
}

// ---------------- kernel 1: x row-quant (blocks 0..8191) + |w| partial sums
// (blocks 8192..9215) — independent work fused into one dispatch ------------
__global__ void k_xq_wsum(const float* __restrict__ x, char* __restrict__ qx,
                          float* __restrict__ sx,
                          const float* __restrict__ w, double* __restrict__ partials) {
  if (blockIdx.x >= 8192) {
    // ---- wsum path: 1024 blocks over 4194304 float4 ----
    int wb = blockIdx.x - 8192;
    const float4* w4 = (const float4*)w;
    int tid = wb * 256 + threadIdx.x;                // 262144 threads
    double s = 0.0;
    for (int i = tid; i < 4194304; i += 262144) {    // 16 iters
      float4 v = w4[i];
      s += (double)fabsf(v.x) + (double)fabsf(v.y) +
           (double)fabsf(v.z) + (double)fabsf(v.w);
    }
    for (int off = 32; off > 0; off >>= 1) s += __shfl_down(s, off);
    __shared__ double lsum[4];
    int lane = threadIdx.x & 63, wid = threadIdx.x >> 6;
    if (lane == 0) lsum[wid] = s;
    __syncthreads();
    if (threadIdx.x == 0)
      partials[wb] = lsum[0] + lsum[1] + lsum[2] + lsum[3];
    return;
  }
  // ---- xq path: one row per block ----
  int row = blockIdx.x;
  const float4* xr = (const float4*)(x + (size_t)row * K_DIM);
  float4 v[4];
  float m = 0.f;
#pragma unroll
  for (int c = 0; c < 4; c++) {
    v[c] = xr[threadIdx.x + c * 256];
    m = fmaxf(m, fmaxf(fmaxf(fabsf(v[c].x), fabsf(v[c].y)),
                       fmaxf(fabsf(v[c].z), fabsf(v[c].w))));
  }
  for (int off = 32; off > 0; off >>= 1) m = fmaxf(m, __shfl_down(m, off));
  __shared__ float lm[4];
  __shared__ float bscale;
  int lane = threadIdx.x & 63, wid = threadIdx.x >> 6;
  if (lane == 0) lm[wid] = m;
  __syncthreads();
  if (threadIdx.x == 0) {
    float mm = fmaxf(fmaxf(lm[0], lm[1]), fmaxf(lm[2], lm[3]));
    float sc = fmaxf(mm / 127.0f, 1e-8f);            // exact scale (matches ref)
    bscale = sc;
    sx[row] = sc;
  }
  __syncthreads();
  // reciprocal multiply: a +-1 flip in qx costs only sx*sw ~ 2.5e-4 in out
  float inv = 1.0f / bscale;
  int* q4 = (int*)(qx + (size_t)row * K_DIM);
#pragma unroll
  for (int c = 0; c < 4; c++) {
    int a = (int)fmaxf(fminf(rintf(v[c].x * inv), 127.f), -127.f);
    int b = (int)fmaxf(fminf(rintf(v[c].y * inv), 127.f), -127.f);
    int cc = (int)fmaxf(fminf(rintf(v[c].z * inv), 127.f), -127.f);
    int e = (int)fmaxf(fminf(rintf(v[c].w * inv), 127.f), -127.f);
    q4[threadIdx.x + c * 256] = (a & 255) | ((b & 255) << 8) | ((cc & 255) << 16) | ((e & 255) << 24);
  }
}

// ---------------- kernel 2: reduce partials -> scale; ternary-quantize w ----
__global__ void k_wq(const float* __restrict__ w, const double* __restrict__ partials,
                     float* __restrict__ wscale, char* __restrict__ qw) {
  double s = 0.0;
  for (int i = threadIdx.x; i < 1024; i += 256) s += partials[i];
  for (int off = 32; off > 0; off >>= 1) s += __shfl_down(s, off);
  __shared__ double lsum[4];
  __shared__ float bsc;
  int lane = threadIdx.x & 63, wid = threadIdx.x >> 6;
  if (lane == 0) lsum[wid] = s;
  __syncthreads();
  if (threadIdx.x == 0) {
    double tot = lsum[0] + lsum[1] + lsum[2] + lsum[3];
    float sc = (float)(tot / 16777216.0);            // mean(|w|)
    bsc = sc;
    if (blockIdx.x == 0) *wscale = sc;               // raw scale for epilogue
  }
  __syncthreads();
  float d = bsc + 1e-8f;                             // ref divisor
  const float4* w4 = (const float4*)w;
  int* q4 = (int*)qw;
  int tid = blockIdx.x * 256 + threadIdx.x;          // 524288 threads
  for (int i = tid; i < 4194304; i += 524288) {      // 8 iters
    float4 v = w4[i];
    // exact fp32 division + rint: a ternary flip costs ~0.04 in out — keep exact
    int a = (int)fmaxf(fminf(rintf(v.x / d), 1.f), -1.f);
    int b = (int)fmaxf(fminf(rintf(v.y / d), 1.f), -1.f);
    int c = (int)fmaxf(fminf(rintf(v.z / d), 1.f), -1.f);
    int e = (int)fmaxf(fminf(rintf(v.w / d), 1.f), -1.f);
    q4[i] = (a & 255) | ((b & 255) << 8) | ((c & 255) << 16) | ((e & 255) << 24);
  }
}

// ---------------- kernel 3: int8 MFMA GEMM, swizzled LDS --------------------
// 128x128 C-tile, 4 waves (2x2 of 64x64), BK=64 int8.
// Per operand per k-iter: 8 chunks of 1024B; chunk c = rows [c*16,c*16+16).
// Within a chunk, position p (16B units) holds (row r = p>>2,
// kseg q = ((p&3) - (p>>3 & 3)) & 3); i.e. pos(r,q) = 4r + ((q + (r>>1)) & 3).
//  - staging: lane quads cover one 64B row segment (coalesced global)
//  - compute: lane octets hit 8 distinct bank quads (conflict-free ds_read_b128)
__global__ void k_gemm(const char* __restrict__ qx, const char* __restrict__ qw,
                       const float* __restrict__ sx, const float* __restrict__ wscale,
                       float* __restrict__ out) {
  __shared__ char ldsA[8192];
  __shared__ char ldsB[8192];

  const int bn = blockIdx.x & 31;          // 32 tiles along N
  const int bm = blockIdx.x >> 5;          // 64 tiles along M
  const int rowBase = bm * 128;
  const int colBase = bn * 128;
  const int lane = threadIdx.x & 63;
  const int wave = threadIdx.x >> 6;
  const int wr = wave >> 1, wc = wave & 1;

  v4i acc[4][4] = {};

  // staging: wave w stages chunks 2w,2w+1 of each operand.
  // lane ls -> global (row ls>>2, kseg ((ls&3) - ((ls>>3)&3)) & 3)
  const int sR = lane >> 2;
  const int sQ = ((lane & 3) - ((lane >> 3) & 3)) & 3;
  const char* gA0 = qx + (size_t)(rowBase + wave * 32 + sR) * K_DIM + sQ * 16;
  const char* gA1 = gA0 + 16 * K_DIM;
  const char* gB0 = qw + (size_t)(colBase + wave * 32 + sR) * K_DIM + sQ * 16;
  const char* gB1 = gB0 + 16 * K_DIM;
  char* lA0 = ldsA + wave * 2048;          // wave-uniform LDS bases
  char* lA1 = lA0 + 1024;
  char* lB0 = ldsB + wave * 2048;
  char* lB1 = lB0 + 1024;

  // compute: lane l wants (r=l&15, q=l>>4) -> pos = 4r + ((q + (r>>1)) & 3)
  const int fr = lane & 15, fq = lane >> 4;
  const int posOff = (4 * fr + ((fq + (fr >> 1)) & 3)) * 16;
  const char* aBase = ldsA + wr * 4096 + posOff;
  const char* bBase = ldsB + wc * 4096 + posOff;

  for (int kb = 0; kb < K_DIM / 64; kb++) {
    if (kb) __syncthreads();
    const int goff = kb * 64;
    async_copy16(lA0, gA0 + goff);
    async_copy16(lA1, gA1 + goff);
    async_copy16(lB0, gB0 + goff);
    async_copy16(lB1, gB1 + goff);
    __syncthreads();                       // drains vmcnt for the DMA

    v4i a[4], b[4];
#pragma unroll
    for (int t = 0; t < 4; t++) {
      a[t] = *(const v4i*)(aBase + t * 1024);
      b[t] = *(const v4i*)(bBase + t * 1024);
    }
#pragma unroll
    for (int mt = 0; mt < 4; mt++)
#pragma unroll
      for (int nt = 0; nt < 4; nt++)
        acc[mt][nt] = __builtin_amdgcn_mfma_i32_16x16x64_i8(a[mt], b[nt], acc[mt][nt], 0, 0, 0);
  }

  // epilogue: C/D 16x16 layout col=lane&15, row=(lane>>4)*4+reg
  const float sw = *wscale;
  const int col0 = colBase + wc * 64 + (lane & 15);
  const int row0 = rowBase + wr * 64 + (lane >> 4) * 4;
#pragma unroll
  for (int mt = 0; mt < 4; mt++) {
#pragma unroll
    for (int r = 0; r < 4; r++) {
      const int row = row0 + mt * 16 + r;
      const float s = sx[row] * sw;
#pragma unroll
      for (int nt = 0; nt < 4; nt++)
        out[(size_t)row * N_DIM + col0 + nt * 16] = (float)acc[mt][nt][r] * s;
    }
  }
}

// ---------------- launcher ---------------------------------------------------
extern "C" void kernel_launch(void* const* d_in, const int* in_sizes, int n_in,
                              void* d_out, int out_size, void* d_ws, size_t ws_size,
                              hipStream_t stream) {
  const float* x = (const float*)d_in[0];   // [2,4096,4096]
  const float* w = (const float*)d_in[1];   // [4096,4096]
  float* out = (float*)d_out;               // [2,4096,4096]
  char* ws = (char*)d_ws;

  double* partials = (double*)ws;                  // 1024 doubles
  float* wscale    = (float*)(ws + 8192);          // 1 float
  float* sx        = (float*)(ws + 8448);          // 8192 floats
  char*  qw        = ws + 41472;                   // 16 MiB
  char*  qx        = ws + 41472 + 16777216;        // 32 MiB

  k_xq_wsum <<<9216, 256, 0, stream>>>(x, qx, sx, w, partials);
  k_wq      <<<2048, 256, 0, stream>>>(w, partials, wscale, qw);
  k_gemm    <<<64 * 32, 256, 0, stream>>>(qx, qw, sx, wscale, out);
}